// Round 3
// baseline (453.767 us; speedup 1.0000x reference)
//
#include <hip/hip_runtime.h>

// B=8, S=2048, D=512, H=8, Hd=64.
typedef _Float16 half8 __attribute__((ext_vector_type(8)));
typedef _Float16 half4 __attribute__((ext_vector_type(4)));
typedef __fp16 fp16x2 __attribute__((ext_vector_type(2)));
typedef float floatx16 __attribute__((ext_vector_type(16)));
typedef unsigned int uint2v __attribute__((ext_vector_type(2)));

#define MFMA_F16 __builtin_amdgcn_mfma_f32_32x32x16_f16

__device__ __forceinline__ float fast_exp2(float x) {
#if __has_builtin(__builtin_amdgcn_exp2f)
    return __builtin_amdgcn_exp2f(x);     // bare v_exp_f32, args bounded
#else
    return exp2f(x);
#endif
}

// pack 4 fp32 -> half4 via 2x v_cvt_pkrtz (RTZ; rel err ~2^-11, negligible)
__device__ __forceinline__ half4 pack4(float a, float b, float c, float d) {
    union { fp16x2 p[2]; half4 h; } u;
    u.p[0] = __builtin_amdgcn_cvt_pkrtz(a, b);
    u.p[1] = __builtin_amdgcn_cvt_pkrtz(c, d);
    return u.h;
}

// pack 2 fp32 -> one dword of 2 fp16
__device__ __forceinline__ unsigned int pk2(float a, float b) {
    union { fp16x2 p; unsigned int u; } v;
    v.p = __builtin_amdgcn_cvt_pkrtz(a, b);
    return v.u;
}

// 8 contiguous halfs from LDS, two b64 reads (row stride 68 halfs = 136 B ->
// bank shift 2/row -> 2-way conflict, free per m136).
__device__ __forceinline__ half8 ld_frag_lds(const _Float16* p) {
    union { half8 v; half4 h[2]; } u;
    u.h[0] = *(const half4*)(p);
    u.h[1] = *(const half4*)(p + 4);
    return u.v;
}

// Raw workgroup barrier that does NOT drain vmcnt (T4): cross-wave ordering
// here is LDS-only (stage F(t) -> read B/C(t+1); read B/C(t) -> overwrite
// F(t+1)), so lgkmcnt(0) suffices.  Global prefetch loads (G phase) are
// consumed only by this wave's own F next iter — the compiler's per-use
// vmcnt wait covers them, and they stay in flight across the barrier
// (__syncthreads would force vmcnt(0) here: the structural ~20% drain stall).
// "memory" clobbers pin LDS ops on both sides of the barrier.
__device__ __forceinline__ void tile_barrier() {
    asm volatile("s_waitcnt lgkmcnt(0)" ::: "memory");
    __builtin_amdgcn_s_barrier();
    asm volatile("" ::: "memory");
}

// Assemble PV B-operand fragment kc from packed-P words via permlane32_swap
// (T12).  w holds 16 dwords: index i = ms*4+g (g = k-octet within 32-block,
// split by lane-half).  Fragment kc needs index i = 4*(kc>>1)+2*(kc&1)+lh
// with words from BOTH lane halves; the swap of (w[i0], w[i0+1]) returns
// exactly (own-half sel by lh, partner-half sel by lh).
__device__ __forceinline__ half8 pv_frag(const unsigned int* w, int i0) {
    uint2v s0 = __builtin_amdgcn_permlane32_swap(w[2 * i0 + 0], w[2 * i0 + 2], false, false);
    uint2v s1 = __builtin_amdgcn_permlane32_swap(w[2 * i0 + 1], w[2 * i0 + 3], false, false);
    union { unsigned int u[4]; half8 h; } pu;
    pu.u[0] = s0[0];   // k = 16kc+8lh+{0,1}  (from lh'=0)
    pu.u[1] = s1[0];   // k = 16kc+8lh+{2,3}
    pu.u[2] = s0[1];   // k = 16kc+8lh+{4,5}  (from lh'=1)
    pu.u[3] = s1[1];   // k = 16kc+8lh+{6,7}
    return pu.h;
}

// ---------------------------------------------------------------------------
// Weight transpose+convert via LDS tile.  fp32 W[in][out] -> fp16 Wt[out][in].
// Grid: 4 matrices x 64 tiles of 64x64.
// ---------------------------------------------------------------------------
__global__ __launch_bounds__(256) void wcvt_kernel(const float* __restrict__ Wq,
                                                   const float* __restrict__ Wk,
                                                   const float* __restrict__ Wv,
                                                   const float* __restrict__ Wo,
                                                   _Float16* __restrict__ Wt) {
    __shared__ _Float16 T[64 * 68];
    const int bx   = blockIdx.x;
    const int wsel = bx >> 6;
    const int tile = bx & 63;
    const int to   = (tile >> 3) * 64;   // out-tile base
    const int ti   = (tile & 7) * 64;    // in-tile base
    const float* src = (wsel == 0) ? Wq : (wsel == 1) ? Wk : (wsel == 2) ? Wv : Wo;
    const int t = threadIdx.x;
    const int rloc = t >> 4, c4 = (t & 15) * 4;
#pragma unroll
    for (int m = 0; m < 4; m++) {
        int i = ti + rloc + 16 * m;                       // coalesced row read
        float4 f = *(const float4*)(src + (size_t)i * 512 + to + c4);
        T[(c4 + 0) * 68 + rloc + 16 * m] = (_Float16)f.x; // transposed into LDS
        T[(c4 + 1) * 68 + rloc + 16 * m] = (_Float16)f.y;
        T[(c4 + 2) * 68 + rloc + 16 * m] = (_Float16)f.z;
        T[(c4 + 3) * 68 + rloc + 16 * m] = (_Float16)f.w;
    }
    __syncthreads();
    const int o_loc = t >> 2, ich = (t & 3) * 16;
    const _Float16* s = &T[o_loc * 68 + ich];
    _Float16* dst = Wt + (size_t)wsel * 262144 + (size_t)(to + o_loc) * 512 + ti + ich;
    half4 a0 = *(const half4*)(s);
    half4 a1 = *(const half4*)(s + 4);
    half4 a2 = *(const half4*)(s + 8);
    half4 a3 = *(const half4*)(s + 12);
    *(half4*)(dst)      = a0;                             // coalesced write
    *(half4*)(dst + 4)  = a1;
    *(half4*)(dst + 8)  = a2;
    *(half4*)(dst + 12) = a3;
}

// ---------------------------------------------------------------------------
// Merged Q/K/V projection GEMM: C[16384x512] = A * Wt[z] (fp16).
// grid (4, 128, 3): z=0 query->Qh (*C1), z=1 key->Kh, z=2 value->Vt (transposed).
// Tile 128x128, BK=64, 4 waves of 64x64.  A and B register-prefetched.
// ---------------------------------------------------------------------------
__global__ __launch_bounds__(256, 3) void qkv_gemm(const float* __restrict__ query,
                                                   const float* __restrict__ key,
                                                   const float* __restrict__ value,
                                                   const _Float16* __restrict__ Wt,
                                                   _Float16* __restrict__ Qh,
                                                   _Float16* __restrict__ Kh,
                                                   _Float16* __restrict__ Vt,
                                                   float C1) {
    __shared__ _Float16 Alds[128 * 68];
    __shared__ _Float16 Blds[128 * 68];

    const int z = blockIdx.z;
    const float* A = (z == 0) ? query : (z == 1) ? key : value;
    const _Float16* W = Wt + (size_t)z * 262144;

    const int tid  = threadIdx.x;
    const int lane = tid & 63;
    const int w    = tid >> 6;
    const int l31  = lane & 31;
    const int lh   = lane >> 5;
    const int wm   = w >> 1;
    const int wn   = w & 1;
    const int n0   = blockIdx.x * 128;
    const int m0   = blockIdx.y * 128;
    const int crow = tid >> 3;
    const int ck8  = (tid & 7) * 8;

    floatx16 acc[2][2];
#pragma unroll
    for (int i = 0; i < 2; i++)
#pragma unroll
        for (int j = 0; j < 2; j++)
#pragma unroll
            for (int r = 0; r < 16; r++) acc[i][j][r] = 0.0f;

    float4 apre[4][2];
    int4   bpre[4];
#pragma unroll
    for (int i = 0; i < 4; i++) {
        const float* p = A + (size_t)(m0 + crow + 32 * i) * 512 + ck8;
        apre[i][0] = *(const float4*)(p);
        apre[i][1] = *(const float4*)(p + 4);
        bpre[i] = *(const int4*)(W + (size_t)(n0 + crow + 32 * i) * 512 + ck8);
    }

    for (int t = 0; t < 8; t++) {
        __syncthreads();                       // all waves done reading prev tile
#pragma unroll
        for (int i = 0; i < 4; i++) {
            int r = crow + 32 * i;
            float4 f0 = apre[i][0], f1 = apre[i][1];
            *(half4*)&Alds[r * 68 + ck8]     = pack4(f0.x, f0.y, f0.z, f0.w);
            *(half4*)&Alds[r * 68 + ck8 + 4] = pack4(f1.x, f1.y, f1.z, f1.w);
            *(int2*)&Blds[r * 68 + ck8]      = make_int2(bpre[i].x, bpre[i].y);
            *(int2*)&Blds[r * 68 + ck8 + 4]  = make_int2(bpre[i].z, bpre[i].w);
        }
        __syncthreads();
        if (t < 7) {                           // prefetch t+1; waited next iter
            int ks2 = (t + 1) * 64;
#pragma unroll
            for (int i = 0; i < 4; i++) {
                const float* p = A + (size_t)(m0 + crow + 32 * i) * 512 + ks2 + ck8;
                apre[i][0] = *(const float4*)(p);
                apre[i][1] = *(const float4*)(p + 4);
                bpre[i] = *(const int4*)(W + (size_t)(n0 + crow + 32 * i) * 512 + ks2 + ck8);
            }
        }
#pragma unroll
        for (int kc = 0; kc < 4; kc++) {
            int kb = kc * 16 + lh * 8;
            half8 af[2], bf[2];
            af[0] = ld_frag_lds(&Alds[(wm * 64 + l31) * 68 + kb]);
            af[1] = ld_frag_lds(&Alds[(wm * 64 + 32 + l31) * 68 + kb]);
            bf[0] = ld_frag_lds(&Blds[(wn * 64 + l31) * 68 + kb]);
            bf[1] = ld_frag_lds(&Blds[(wn * 64 + 32 + l31) * 68 + kb]);
#pragma unroll
            for (int i = 0; i < 2; i++)
#pragma unroll
                for (int j = 0; j < 2; j++)
                    acc[i][j] = MFMA_F16(af[i], bf[j], acc[i][j], 0, 0, 0);
        }
    }

    // epilogue: C/D layout col=lane&31, row=(r&3)+8*(r>>2)+4*lh
    const float oscale = (z == 0) ? C1 : 1.0f;
    _Float16* out01 = (z == 0) ? Qh : Kh;
#pragma unroll
    for (int i = 0; i < 2; i++) {
#pragma unroll
        for (int j = 0; j < 2; j++) {
            int gn    = n0 + wn * 64 + j * 32 + l31;
            int mbase = m0 + wm * 64 + i * 32 + 4 * lh;
            int h = gn >> 6, hd = gn & 63;
            if (z < 2) {   // Q/K: [b,h,s,hd]
#pragma unroll
                for (int r = 0; r < 16; r++) {
                    int gm = mbase + (r & 3) + 8 * (r >> 2);
                    int b = gm >> 11, s = gm & 2047;
                    out01[(size_t)((b * 8 + h) * 2048 + s) * 64 + hd] =
                        (_Float16)(acc[i][j][r] * oscale);
                }
            } else {       // V: transposed [b,h,hd,s], s packed 4-wide
#pragma unroll
                for (int g = 0; g < 4; g++) {
                    int gm = mbase + 8 * g;
                    int b = gm >> 11, s = gm & 2047;
                    *(half4*)&Vt[(size_t)((b * 8 + h) * 64 + hd) * 2048 + s] =
                        pack4(acc[i][j][4 * g + 0], acc[i][j][4 * g + 1],
                              acc[i][j][4 * g + 2], acc[i][j][4 * g + 3]);
                }
            }
        }
    }
}

// ---------------------------------------------------------------------------
// Output projection: out[16384x512] fp32 = AO(fp16) * Wt_o + bias.
// ---------------------------------------------------------------------------
__global__ __launch_bounds__(256, 3) void out_gemm(const _Float16* __restrict__ A,
                                                   const _Float16* __restrict__ W,
                                                   const float* __restrict__ bias,
                                                   float* __restrict__ out) {
    __shared__ _Float16 Alds[128 * 68];
    __shared__ _Float16 Blds[128 * 68];

    const int tid  = threadIdx.x;
    const int lane = tid & 63;
    const int w    = tid >> 6;
    const int l31  = lane & 31;
    const int lh   = lane >> 5;
    const int wm   = w >> 1;
    const int wn   = w & 1;
    const int n0   = blockIdx.x * 128;
    const int m0   = blockIdx.y * 128;
    const int crow = tid >> 3;
    const int ck8  = (tid & 7) * 8;

    floatx16 acc[2][2];
#pragma unroll
    for (int i = 0; i < 2; i++)
#pragma unroll
        for (int j = 0; j < 2; j++)
#pragma unroll
            for (int r = 0; r < 16; r++) acc[i][j][r] = 0.0f;

    int4 apre[4], bpre[4];
#pragma unroll
    for (int i = 0; i < 4; i++) {
        apre[i] = *(const int4*)(A + (size_t)(m0 + crow + 32 * i) * 512 + ck8);
        bpre[i] = *(const int4*)(W + (size_t)(n0 + crow + 32 * i) * 512 + ck8);
    }

    for (int t = 0; t < 8; t++) {
        __syncthreads();
#pragma unroll
        for (int i = 0; i < 4; i++) {
            int r = crow + 32 * i;
            *(int2*)&Alds[r * 68 + ck8]     = make_int2(apre[i].x, apre[i].y);
            *(int2*)&Alds[r * 68 + ck8 + 4] = make_int2(apre[i].z, apre[i].w);
            *(int2*)&Blds[r * 68 + ck8]     = make_int2(bpre[i].x, bpre[i].y);
            *(int2*)&Blds[r * 68 + ck8 + 4] = make_int2(bpre[i].z, bpre[i].w);
        }
        __syncthreads();
        if (t < 7) {
            int ks2 = (t + 1) * 64;
#pragma unroll
            for (int i = 0; i < 4; i++) {
                apre[i] = *(const int4*)(A + (size_t)(m0 + crow + 32 * i) * 512 + ks2 + ck8);
                bpre[i] = *(const int4*)(W + (size_t)(n0 + crow + 32 * i) * 512 + ks2 + ck8);
            }
        }
#pragma unroll
        for (int kc = 0; kc < 4; kc++) {
            int kb = kc * 16 + lh * 8;
            half8 af[2], bf[2];
            af[0] = ld_frag_lds(&Alds[(wm * 64 + l31) * 68 + kb]);
            af[1] = ld_frag_lds(&Alds[(wm * 64 + 32 + l31) * 68 + kb]);
            bf[0] = ld_frag_lds(&Blds[(wn * 64 + l31) * 68 + kb]);
            bf[1] = ld_frag_lds(&Blds[(wn * 64 + 32 + l31) * 68 + kb]);
#pragma unroll
            for (int i = 0; i < 2; i++)
#pragma unroll
                for (int j = 0; j < 2; j++)
                    acc[i][j] = MFMA_F16(af[i], bf[j], acc[i][j], 0, 0, 0);
        }
    }

#pragma unroll
    for (int i = 0; i < 2; i++) {
#pragma unroll
        for (int j = 0; j < 2; j++) {
            int gn    = n0 + wn * 64 + j * 32 + l31;
            int mbase = m0 + wm * 64 + i * 32 + 4 * lh;
            float bv = bias[gn];
#pragma unroll
            for (int r = 0; r < 16; r++) {
                int gm = mbase + (r & 3) + 8 * (r >> 2);
                out[(size_t)gm * 512 + gn] = acc[i][j][r] + bv;
            }
        }
    }
}

// ---------------------------------------------------------------------------
// Flash attention, static softmax, 1-tile software skew (R1 structure).
// Per iteration t (one barrier each):
//   D: PV(t-1) MFMA (P assembled in-register via permlane32_swap — T12;
//      V frags held in regs from iter t-1)
//   F: stage tile t+1 into K/V buf[t+1&1]   G: global prefetch tile t+2
//   B: V frags(t) LDS->regs   C: S-MFMA(t)   E: exp+pack P(t) into regs
// Round-3 deltas vs R1:
//   - tile_barrier(): lgkmcnt-only barrier, G-phase global loads stay in
//     flight across it (T4 counted-vmcnt mechanism).
//   - __launch_bounds__(256,4): grid is exactly 1024 = 4 blocks/CU; at
//     84 VGPR + 34.8 KB LDS all 4 fit -> whole grid co-resident, no tail.
//   - T5 s_setprio(1) around both MFMA clusters.
// ---------------------------------------------------------------------------
__global__ __launch_bounds__(256, 4) void attn_kernel(const _Float16* __restrict__ Qg,
                                                      const _Float16* __restrict__ Kg,
                                                      const _Float16* __restrict__ Vg,
                                                      _Float16* __restrict__ AO) {
    __shared__ _Float16 Kbuf[2][64 * 68];
    __shared__ _Float16 Vbuf[2][64 * 68];

    const int tid  = threadIdx.x;
    const int lane = tid & 63;
    const int w    = tid >> 6;
    const int l31  = lane & 31;
    const int lh   = lane >> 5;
    const int h    = blockIdx.y;
    const int b    = blockIdx.z;
    const int q0   = blockIdx.x * 128 + w * 32;

    const size_t bhoff = (size_t)(b * 8 + h) * (2048 * 64);
    const _Float16* Qbh = Qg + bhoff;
    const _Float16* Kbh = Kg + bhoff;
    const _Float16* Vbh = Vg + bhoff;   // [hd][s]

    const int c0row = tid >> 3, ck8 = (tid & 7) * 8;   // staging coords
    const int c1row = c0row + 32;

    // Q B-operand frags (lane=q, k=hd), loop-invariant, pre-scaled by C1.
    half8 qf[4];
#pragma unroll
    for (int kc = 0; kc < 4; kc++)
        qf[kc] = *(const half8*)(Qbh + (size_t)(q0 + l31) * 64 + kc * 16 + lh * 8);

    floatx16 O[2];
#pragma unroll
    for (int i = 0; i < 2; i++)
#pragma unroll
        for (int r = 0; r < 16; r++) O[i][r] = 0.0f;
    float lsum = 0.0f;

    unsigned int w16[16];   // P of tile t-1, packed fp16 words (reg-resident)
    half8 vf[4][2];         // V^T A-operand frags of tile t-1 (reg)

    // ---- prologue: stage tile 0, prefetch tile 1 ----
    int4 kpre[2], vpre[2];
    kpre[0] = *(const int4*)(Kbh + c0row * 64 + ck8);
    kpre[1] = *(const int4*)(Kbh + c1row * 64 + ck8);
    vpre[0] = *(const int4*)(Vbh + (size_t)c0row * 2048 + ck8);
    vpre[1] = *(const int4*)(Vbh + (size_t)c1row * 2048 + ck8);
    *(int2*)&Kbuf[0][c0row * 68 + ck8]     = make_int2(kpre[0].x, kpre[0].y);
    *(int2*)&Kbuf[0][c0row * 68 + ck8 + 4] = make_int2(kpre[0].z, kpre[0].w);
    *(int2*)&Kbuf[0][c1row * 68 + ck8]     = make_int2(kpre[1].x, kpre[1].y);
    *(int2*)&Kbuf[0][c1row * 68 + ck8 + 4] = make_int2(kpre[1].z, kpre[1].w);
    *(int2*)&Vbuf[0][c0row * 68 + ck8]     = make_int2(vpre[0].x, vpre[0].y);
    *(int2*)&Vbuf[0][c0row * 68 + ck8 + 4] = make_int2(vpre[0].z, vpre[0].w);
    *(int2*)&Vbuf[0][c1row * 68 + ck8]     = make_int2(vpre[1].x, vpre[1].y);
    *(int2*)&Vbuf[0][c1row * 68 + ck8 + 4] = make_int2(vpre[1].z, vpre[1].w);
    kpre[0] = *(const int4*)(Kbh + 4096 + c0row * 64 + ck8);
    kpre[1] = *(const int4*)(Kbh + 4096 + c1row * 64 + ck8);
    vpre[0] = *(const int4*)(Vbh + 64 + (size_t)c0row * 2048 + ck8);
    vpre[1] = *(const int4*)(Vbh + 64 + (size_t)c1row * 2048 + ck8);
    tile_barrier();

    for (int kt = 0; kt < 32; kt++) {
        const int cur = kt & 1;
        const _Float16* Kc = Kbuf[cur];
        const _Float16* Vc = Vbuf[cur];

        if (kt > 0) {
            // D: O += V^T(t-1) * P(t-1); P assembled in-register (permlane)
            __builtin_amdgcn_s_setprio(1);
#pragma unroll
            for (int kc = 0; kc < 4; kc++) {
                int i0 = (kc >> 1) * 4 + (kc & 1) * 2;
                half8 pf = pv_frag(w16, i0);
                O[0] = MFMA_F16(vf[kc][0], pf, O[0], 0, 0, 0);
                O[1] = MFMA_F16(vf[kc][1], pf, O[1], 0, 0, 0);
            }
            __builtin_amdgcn_s_setprio(0);
        }

        // F: stage tile t+1 into the other buffer (regs hold tile t+1)
        if (kt < 31) {
            _Float16* Kd = Kbuf[cur ^ 1];
            _Float16* Vd = Vbuf[cur ^ 1];
            *(int2*)&Kd[c0row * 68 + ck8]     = make_int2(kpre[0].x, kpre[0].y);
            *(int2*)&Kd[c0row * 68 + ck8 + 4] = make_int2(kpre[0].z, kpre[0].w);
            *(int2*)&Kd[c1row * 68 + ck8]     = make_int2(kpre[1].x, kpre[1].y);
            *(int2*)&Kd[c1row * 68 + ck8 + 4] = make_int2(kpre[1].z, kpre[1].w);
            *(int2*)&Vd[c0row * 68 + ck8]     = make_int2(vpre[0].x, vpre[0].y);
            *(int2*)&Vd[c0row * 68 + ck8 + 4] = make_int2(vpre[0].z, vpre[0].w);
            *(int2*)&Vd[c1row * 68 + ck8]     = make_int2(vpre[1].x, vpre[1].y);
            *(int2*)&Vd[c1row * 68 + ck8 + 4] = make_int2(vpre[1].z, vpre[1].w);
        }
        // G: prefetch tile t+2 (rides across tile_barrier — no vmcnt drain)
        if (kt < 30) {
            const _Float16* Ksrc = Kbh + (size_t)(kt + 2) * 4096;
            const _Float16* Vsrc = Vbh + (size_t)(kt + 2) * 64;
            kpre[0] = *(const int4*)(Ksrc + c0row * 64 + ck8);
            kpre[1] = *(const int4*)(Ksrc + c1row * 64 + ck8);
            vpre[0] = *(const int4*)(Vsrc + (size_t)c0row * 2048 + ck8);
            vpre[1] = *(const int4*)(Vsrc + (size_t)c1row * 2048 + ck8);
        }

        // B: V frags(t) -> regs (used for PV at iter t+1; buffer gets
        // overwritten at iter t+1, so read now)
#pragma unroll
        for (int kc = 0; kc < 4; kc++) {
            vf[kc][0] = ld_frag_lds(&Vc[(l31)*68      + kc * 16 + lh * 8]);
            vf[kc][1] = ld_frag_lds(&Vc[(32 + l31)*68 + kc * 16 + lh * 8]);
        }

        // C: S^T(t) = K * Q^T  (kc-outer: the two ms-chains interleave)
        floatx16 Sf[2];
#pragma unroll
        for (int i = 0; i < 2; i++)
#pragma unroll
            for (int r = 0; r < 16; r++) Sf[i][r] = 0.0f;
        __builtin_amdgcn_s_setprio(1);
#pragma unroll
        for (int kc = 0; kc < 4; kc++) {
#pragma unroll
            for (int ms = 0; ms < 2; ms++) {
                half8 kf = ld_frag_lds(&Kc[(ms * 32 + l31) * 68 + kc * 16 + lh * 8]);
                Sf[ms] = MFMA_F16(kf, qf[kc], Sf[ms], 0, 0, 0);
            }
        }
        __builtin_amdgcn_s_setprio(0);

        // E: static softmax — P(t) = exp2(S), pack to regs, accumulate l
        float rsA = 0.0f, rsB = 0.0f;
#pragma unroll
        for (int i = 0; i < 8; i++) {
            int ms = i >> 2, g = i & 3;
            float p0 = fast_exp2(Sf[ms][4 * g + 0]);
            float p1 = fast_exp2(Sf[ms][4 * g + 1]);
            float p2 = fast_exp2(Sf[ms][4 * g + 2]);
            float p3 = fast_exp2(Sf[ms][4 * g + 3]);
            rsA += p0 + p1;
            rsB += p2 + p3;
            w16[2 * i + 0] = pk2(p0, p1);
            w16[2 * i + 1] = pk2(p2, p3);
        }
        lsum += rsA + rsB;

        tile_barrier();
    }

    // ---- epilogue: PV for the last tile (register-only, no barrier) ----
    __builtin_amdgcn_s_setprio(1);
#pragma unroll
    for (int kc = 0; kc < 4; kc++) {
        int i0 = (kc >> 1) * 4 + (kc & 1) * 2;
        half8 pf = pv_frag(w16, i0);
        O[0] = MFMA_F16(vf[kc][0], pf, O[0], 0, 0, 0);
        O[1] = MFMA_F16(vf[kc][1], pf, O[1], 0, 0, 0);
    }
    __builtin_amdgcn_s_setprio(0);

    // combine key-halves' l (lanes l, l+32 share q), normalize, store
    lsum += __shfl_xor(lsum, 32);
    float inv = 1.0f / lsum;
    int q = q0 + l31;
#pragma unroll
    for (int hs = 0; hs < 2; hs++) {
#pragma unroll
        for (int g = 0; g < 4; g++) {
            *(half4*)&AO[(size_t)(b * 2048 + q) * 512 + h * 64 + hs * 32 + g * 8 + lh * 4] =
                pack4(O[hs][4 * g + 0] * inv, O[hs][4 * g + 1] * inv,
                      O[hs][4 * g + 2] * inv, O[hs][4 * g + 3] * inv);
        }
    }
}

// ---------------------------------------------------------------------------
extern "C" void kernel_launch(void* const* d_in, const int* in_sizes, int n_in,
                              void* d_out, int out_size, void* d_ws, size_t ws_size,
                              hipStream_t stream) {
    const float* key   = (const float*)d_in[0];
    const float* query = (const float*)d_in[1];
    const float* value = (const float*)d_in[2];
    const float* Wq    = (const float*)d_in[3];
    const float* Wk    = (const float*)d_in[4];
    const float* Wv    = (const float*)d_in[5];
    const float* Wo    = (const float*)d_in[6];
    const float* bo    = (const float*)d_in[7];

    // Workspace (halfs): Wt[4*512*512] | Qh | Kh | Vt | AO  (69.2 MB)
    _Float16* ws = (_Float16*)d_ws;
    _Float16* Wt = ws;
    _Float16* Qh = ws + 1048576;
    _Float16* Kh = Qh + 8388608;
    _Float16* Vt = Kh + 8388608;
    _Float16* AO = Vt + 8388608;

    const float C1 = 0.18033688011112042f;   // log2(e)/sqrt(64), folded into Q

    wcvt_kernel<<<dim3(256), dim3(256), 0, stream>>>(Wq, Wk, Wv, Wo, Wt);

    qkv_gemm<<<dim3(4, 128, 3), dim3(256), 0, stream>>>(query, key, value, Wt,
                                                        Qh, Kh, Vt, C1);

    attn_kernel<<<dim3(16, 8, 8), dim3(256), 0, stream>>>(Qh, Kh, Vt, AO);

    out_gemm<<<dim3(4, 128), dim3(256), 0, stream>>>(AO, Wt + 3 * 262144, bo,
                                                     (float*)d_out);
}

// Round 4
// 288.838 us; speedup vs baseline: 1.5710x; 1.5710x over previous
//
#include <hip/hip_runtime.h>

// B=8, S=2048, D=512, H=8, Hd=64.
typedef _Float16 half8 __attribute__((ext_vector_type(8)));
typedef _Float16 half4 __attribute__((ext_vector_type(4)));
typedef __fp16 fp16x2 __attribute__((ext_vector_type(2)));
typedef float floatx16 __attribute__((ext_vector_type(16)));
typedef unsigned int uint2v __attribute__((ext_vector_type(2)));

#define MFMA_F16 __builtin_amdgcn_mfma_f32_32x32x16_f16

__device__ __forceinline__ float fast_exp2(float x) {
#if __has_builtin(__builtin_amdgcn_exp2f)
    return __builtin_amdgcn_exp2f(x);     // bare v_exp_f32, args bounded
#else
    return exp2f(x);
#endif
}

// pack 4 fp32 -> half4 via 2x v_cvt_pkrtz (RTZ; rel err ~2^-11, negligible)
__device__ __forceinline__ half4 pack4(float a, float b, float c, float d) {
    union { fp16x2 p[2]; half4 h; } u;
    u.p[0] = __builtin_amdgcn_cvt_pkrtz(a, b);
    u.p[1] = __builtin_amdgcn_cvt_pkrtz(c, d);
    return u.h;
}

// pack 2 fp32 -> one dword of 2 fp16
__device__ __forceinline__ unsigned int pk2(float a, float b) {
    union { fp16x2 p; unsigned int u; } v;
    v.p = __builtin_amdgcn_cvt_pkrtz(a, b);
    return v.u;
}

// 8 contiguous halfs from LDS, two b64 reads (row stride 68 halfs = 136 B ->
// bank shift 2/row -> 2-way conflict, free per m136).
__device__ __forceinline__ half8 ld_frag_lds(const _Float16* p) {
    union { half8 v; half4 h[2]; } u;
    u.h[0] = *(const half4*)(p);
    u.h[1] = *(const half4*)(p + 4);
    return u.v;
}

// Raw workgroup barrier that does NOT drain vmcnt (T4): cross-wave ordering
// here is LDS-only (stage F(t) -> read B/C(t+1); read B/C(t) -> overwrite
// F(t+1)), so lgkmcnt(0) suffices.  Global prefetch loads (G phase) are
// consumed only by this wave's own F next iter — the compiler's per-use
// vmcnt wait covers them, and they stay in flight across the barrier
// (__syncthreads would force vmcnt(0) here: the structural drain stall).
// Correctness of this protocol was hardware-verified in round 3 (passed).
__device__ __forceinline__ void tile_barrier() {
    asm volatile("s_waitcnt lgkmcnt(0)" ::: "memory");
    __builtin_amdgcn_s_barrier();
    asm volatile("" ::: "memory");
}

// Assemble PV B-operand fragment kc from packed-P words via permlane32_swap
// (T12).  w holds 16 dwords: index i = ms*4+g (g = k-octet within 32-block,
// split by lane-half).  Fragment kc needs index i = 4*(kc>>1)+2*(kc&1)+lh
// with words from BOTH lane halves; the swap of (w[i0], w[i0+1]) returns
// exactly (own-half sel by lh, partner-half sel by lh).
__device__ __forceinline__ half8 pv_frag(const unsigned int* w, int i0) {
    uint2v s0 = __builtin_amdgcn_permlane32_swap(w[2 * i0 + 0], w[2 * i0 + 2], false, false);
    uint2v s1 = __builtin_amdgcn_permlane32_swap(w[2 * i0 + 1], w[2 * i0 + 3], false, false);
    union { unsigned int u[4]; half8 h; } pu;
    pu.u[0] = s0[0];   // k = 16kc+8lh+{0,1}  (from lh'=0)
    pu.u[1] = s1[0];   // k = 16kc+8lh+{2,3}
    pu.u[2] = s0[1];   // k = 16kc+8lh+{4,5}  (from lh'=1)
    pu.u[3] = s1[1];   // k = 16kc+8lh+{6,7}
    return pu.h;
}

// ---------------------------------------------------------------------------
// Weight transpose+convert via LDS tile.  fp32 W[in][out] -> fp16 Wt[out][in].
// Grid: 4 matrices x 64 tiles of 64x64.
// ---------------------------------------------------------------------------
__global__ __launch_bounds__(256) void wcvt_kernel(const float* __restrict__ Wq,
                                                   const float* __restrict__ Wk,
                                                   const float* __restrict__ Wv,
                                                   const float* __restrict__ Wo,
                                                   _Float16* __restrict__ Wt) {
    __shared__ _Float16 T[64 * 68];
    const int bx   = blockIdx.x;
    const int wsel = bx >> 6;
    const int tile = bx & 63;
    const int to   = (tile >> 3) * 64;   // out-tile base
    const int ti   = (tile & 7) * 64;    // in-tile base
    const float* src = (wsel == 0) ? Wq : (wsel == 1) ? Wk : (wsel == 2) ? Wv : Wo;
    const int t = threadIdx.x;
    const int rloc = t >> 4, c4 = (t & 15) * 4;
#pragma unroll
    for (int m = 0; m < 4; m++) {
        int i = ti + rloc + 16 * m;                       // coalesced row read
        float4 f = *(const float4*)(src + (size_t)i * 512 + to + c4);
        T[(c4 + 0) * 68 + rloc + 16 * m] = (_Float16)f.x; // transposed into LDS
        T[(c4 + 1) * 68 + rloc + 16 * m] = (_Float16)f.y;
        T[(c4 + 2) * 68 + rloc + 16 * m] = (_Float16)f.z;
        T[(c4 + 3) * 68 + rloc + 16 * m] = (_Float16)f.w;
    }
    __syncthreads();
    const int o_loc = t >> 2, ich = (t & 3) * 16;
    const _Float16* s = &T[o_loc * 68 + ich];
    _Float16* dst = Wt + (size_t)wsel * 262144 + (size_t)(to + o_loc) * 512 + ti + ich;
    half4 a0 = *(const half4*)(s);
    half4 a1 = *(const half4*)(s + 4);
    half4 a2 = *(const half4*)(s + 8);
    half4 a3 = *(const half4*)(s + 12);
    *(half4*)(dst)      = a0;                             // coalesced write
    *(half4*)(dst + 4)  = a1;
    *(half4*)(dst + 8)  = a2;
    *(half4*)(dst + 12) = a3;
}

// ---------------------------------------------------------------------------
// Merged Q/K/V projection GEMM: C[16384x512] = A * Wt[z] (fp16).
// grid (4, 128, 3): z=0 query->Qh (*C1), z=1 key->Kh, z=2 value->Vt (transposed).
// Tile 128x128, BK=64, 4 waves of 64x64.  A and B register-prefetched.
// ---------------------------------------------------------------------------
__global__ __launch_bounds__(256, 3) void qkv_gemm(const float* __restrict__ query,
                                                   const float* __restrict__ key,
                                                   const float* __restrict__ value,
                                                   const _Float16* __restrict__ Wt,
                                                   _Float16* __restrict__ Qh,
                                                   _Float16* __restrict__ Kh,
                                                   _Float16* __restrict__ Vt,
                                                   float C1) {
    __shared__ _Float16 Alds[128 * 68];
    __shared__ _Float16 Blds[128 * 68];

    const int z = blockIdx.z;
    const float* A = (z == 0) ? query : (z == 1) ? key : value;
    const _Float16* W = Wt + (size_t)z * 262144;

    const int tid  = threadIdx.x;
    const int lane = tid & 63;
    const int w    = tid >> 6;
    const int l31  = lane & 31;
    const int lh   = lane >> 5;
    const int wm   = w >> 1;
    const int wn   = w & 1;
    const int n0   = blockIdx.x * 128;
    const int m0   = blockIdx.y * 128;
    const int crow = tid >> 3;
    const int ck8  = (tid & 7) * 8;

    floatx16 acc[2][2];
#pragma unroll
    for (int i = 0; i < 2; i++)
#pragma unroll
        for (int j = 0; j < 2; j++)
#pragma unroll
            for (int r = 0; r < 16; r++) acc[i][j][r] = 0.0f;

    float4 apre[4][2];
    int4   bpre[4];
#pragma unroll
    for (int i = 0; i < 4; i++) {
        const float* p = A + (size_t)(m0 + crow + 32 * i) * 512 + ck8;
        apre[i][0] = *(const float4*)(p);
        apre[i][1] = *(const float4*)(p + 4);
        bpre[i] = *(const int4*)(W + (size_t)(n0 + crow + 32 * i) * 512 + ck8);
    }

    for (int t = 0; t < 8; t++) {
        __syncthreads();                       // all waves done reading prev tile
#pragma unroll
        for (int i = 0; i < 4; i++) {
            int r = crow + 32 * i;
            float4 f0 = apre[i][0], f1 = apre[i][1];
            *(half4*)&Alds[r * 68 + ck8]     = pack4(f0.x, f0.y, f0.z, f0.w);
            *(half4*)&Alds[r * 68 + ck8 + 4] = pack4(f1.x, f1.y, f1.z, f1.w);
            *(int2*)&Blds[r * 68 + ck8]      = make_int2(bpre[i].x, bpre[i].y);
            *(int2*)&Blds[r * 68 + ck8 + 4]  = make_int2(bpre[i].z, bpre[i].w);
        }
        __syncthreads();
        if (t < 7) {                           // prefetch t+1; waited next iter
            int ks2 = (t + 1) * 64;
#pragma unroll
            for (int i = 0; i < 4; i++) {
                const float* p = A + (size_t)(m0 + crow + 32 * i) * 512 + ks2 + ck8;
                apre[i][0] = *(const float4*)(p);
                apre[i][1] = *(const float4*)(p + 4);
                bpre[i] = *(const int4*)(W + (size_t)(n0 + crow + 32 * i) * 512 + ks2 + ck8);
            }
        }
#pragma unroll
        for (int kc = 0; kc < 4; kc++) {
            int kb = kc * 16 + lh * 8;
            half8 af[2], bf[2];
            af[0] = ld_frag_lds(&Alds[(wm * 64 + l31) * 68 + kb]);
            af[1] = ld_frag_lds(&Alds[(wm * 64 + 32 + l31) * 68 + kb]);
            bf[0] = ld_frag_lds(&Blds[(wn * 64 + l31) * 68 + kb]);
            bf[1] = ld_frag_lds(&Blds[(wn * 64 + 32 + l31) * 68 + kb]);
#pragma unroll
            for (int i = 0; i < 2; i++)
#pragma unroll
                for (int j = 0; j < 2; j++)
                    acc[i][j] = MFMA_F16(af[i], bf[j], acc[i][j], 0, 0, 0);
        }
    }

    // epilogue: C/D layout col=lane&31, row=(r&3)+8*(r>>2)+4*lh
    const float oscale = (z == 0) ? C1 : 1.0f;
    _Float16* out01 = (z == 0) ? Qh : Kh;
#pragma unroll
    for (int i = 0; i < 2; i++) {
#pragma unroll
        for (int j = 0; j < 2; j++) {
            int gn    = n0 + wn * 64 + j * 32 + l31;
            int mbase = m0 + wm * 64 + i * 32 + 4 * lh;
            int h = gn >> 6, hd = gn & 63;
            if (z < 2) {   // Q/K: [b,h,s,hd]
#pragma unroll
                for (int r = 0; r < 16; r++) {
                    int gm = mbase + (r & 3) + 8 * (r >> 2);
                    int b = gm >> 11, s = gm & 2047;
                    out01[(size_t)((b * 8 + h) * 2048 + s) * 64 + hd] =
                        (_Float16)(acc[i][j][r] * oscale);
                }
            } else {       // V: transposed [b,h,hd,s], s packed 4-wide
#pragma unroll
                for (int g = 0; g < 4; g++) {
                    int gm = mbase + 8 * g;
                    int b = gm >> 11, s = gm & 2047;
                    *(half4*)&Vt[(size_t)((b * 8 + h) * 64 + hd) * 2048 + s] =
                        pack4(acc[i][j][4 * g + 0], acc[i][j][4 * g + 1],
                              acc[i][j][4 * g + 2], acc[i][j][4 * g + 3]);
                }
            }
        }
    }
}

// ---------------------------------------------------------------------------
// Output projection: out[16384x512] fp32 = AO(fp16) * Wt_o + bias.
// ---------------------------------------------------------------------------
__global__ __launch_bounds__(256, 3) void out_gemm(const _Float16* __restrict__ A,
                                                   const _Float16* __restrict__ W,
                                                   const float* __restrict__ bias,
                                                   float* __restrict__ out) {
    __shared__ _Float16 Alds[128 * 68];
    __shared__ _Float16 Blds[128 * 68];

    const int tid  = threadIdx.x;
    const int lane = tid & 63;
    const int w    = tid >> 6;
    const int l31  = lane & 31;
    const int lh   = lane >> 5;
    const int wm   = w >> 1;
    const int wn   = w & 1;
    const int n0   = blockIdx.x * 128;
    const int m0   = blockIdx.y * 128;
    const int crow = tid >> 3;
    const int ck8  = (tid & 7) * 8;

    floatx16 acc[2][2];
#pragma unroll
    for (int i = 0; i < 2; i++)
#pragma unroll
        for (int j = 0; j < 2; j++)
#pragma unroll
            for (int r = 0; r < 16; r++) acc[i][j][r] = 0.0f;

    int4 apre[4], bpre[4];
#pragma unroll
    for (int i = 0; i < 4; i++) {
        apre[i] = *(const int4*)(A + (size_t)(m0 + crow + 32 * i) * 512 + ck8);
        bpre[i] = *(const int4*)(W + (size_t)(n0 + crow + 32 * i) * 512 + ck8);
    }

    for (int t = 0; t < 8; t++) {
        __syncthreads();
#pragma unroll
        for (int i = 0; i < 4; i++) {
            int r = crow + 32 * i;
            *(int2*)&Alds[r * 68 + ck8]     = make_int2(apre[i].x, apre[i].y);
            *(int2*)&Alds[r * 68 + ck8 + 4] = make_int2(apre[i].z, apre[i].w);
            *(int2*)&Blds[r * 68 + ck8]     = make_int2(bpre[i].x, bpre[i].y);
            *(int2*)&Blds[r * 68 + ck8 + 4] = make_int2(bpre[i].z, bpre[i].w);
        }
        __syncthreads();
        if (t < 7) {
            int ks2 = (t + 1) * 64;
#pragma unroll
            for (int i = 0; i < 4; i++) {
                apre[i] = *(const int4*)(A + (size_t)(m0 + crow + 32 * i) * 512 + ks2 + ck8);
                bpre[i] = *(const int4*)(W + (size_t)(n0 + crow + 32 * i) * 512 + ks2 + ck8);
            }
        }
#pragma unroll
        for (int kc = 0; kc < 4; kc++) {
            int kb = kc * 16 + lh * 8;
            half8 af[2], bf[2];
            af[0] = ld_frag_lds(&Alds[(wm * 64 + l31) * 68 + kb]);
            af[1] = ld_frag_lds(&Alds[(wm * 64 + 32 + l31) * 68 + kb]);
            bf[0] = ld_frag_lds(&Blds[(wn * 64 + l31) * 68 + kb]);
            bf[1] = ld_frag_lds(&Blds[(wn * 64 + 32 + l31) * 68 + kb]);
#pragma unroll
            for (int i = 0; i < 2; i++)
#pragma unroll
                for (int j = 0; j < 2; j++)
                    acc[i][j] = MFMA_F16(af[i], bf[j], acc[i][j], 0, 0, 0);
        }
    }

#pragma unroll
    for (int i = 0; i < 2; i++) {
#pragma unroll
        for (int j = 0; j < 2; j++) {
            int gn    = n0 + wn * 64 + j * 32 + l31;
            int mbase = m0 + wm * 64 + i * 32 + 4 * lh;
            float bv = bias[gn];
#pragma unroll
            for (int r = 0; r < 16; r++) {
                int gm = mbase + (r & 3) + 8 * (r >> 2);
                out[(size_t)gm * 512 + gn] = acc[i][j][r] + bv;
            }
        }
    }
}

// ---------------------------------------------------------------------------
// Flash attention, static softmax, 1-tile software skew (R1 structure).
// Per iteration t (one barrier each):
//   D: PV(t-1) MFMA (P assembled in-register via permlane32_swap — T12;
//      V frags held in regs from iter t-1)
//   F: stage tile t+1 into K/V buf[t+1&1]   G: global prefetch tile t+2
//   B: V frags(t) LDS->regs   C: S-MFMA(t)   E: exp+pack P(t) into regs
// Round-4 deltas vs R1 (R3 isolated: launch_bounds(256,4) caused spill and
// is reverted; tile_barrier correctness was verified by R3's pass):
//   - tile_barrier(): lgkmcnt-only barrier, G-phase global loads stay in
//     flight across it (T4 mechanism).
//   - T5 s_setprio(1) around both MFMA clusters.
//   - __launch_bounds__(256,3): the verified no-spill operating point
//     (84 VGPR in R1).  Do NOT raise to 4: unified VGPR/AGPR cap spills.
// ---------------------------------------------------------------------------
__global__ __launch_bounds__(256, 3) void attn_kernel(const _Float16* __restrict__ Qg,
                                                      const _Float16* __restrict__ Kg,
                                                      const _Float16* __restrict__ Vg,
                                                      _Float16* __restrict__ AO) {
    __shared__ _Float16 Kbuf[2][64 * 68];
    __shared__ _Float16 Vbuf[2][64 * 68];

    const int tid  = threadIdx.x;
    const int lane = tid & 63;
    const int w    = tid >> 6;
    const int l31  = lane & 31;
    const int lh   = lane >> 5;
    const int h    = blockIdx.y;
    const int b    = blockIdx.z;
    const int q0   = blockIdx.x * 128 + w * 32;

    const size_t bhoff = (size_t)(b * 8 + h) * (2048 * 64);
    const _Float16* Qbh = Qg + bhoff;
    const _Float16* Kbh = Kg + bhoff;
    const _Float16* Vbh = Vg + bhoff;   // [hd][s]

    const int c0row = tid >> 3, ck8 = (tid & 7) * 8;   // staging coords
    const int c1row = c0row + 32;

    // Q B-operand frags (lane=q, k=hd), loop-invariant, pre-scaled by C1.
    half8 qf[4];
#pragma unroll
    for (int kc = 0; kc < 4; kc++)
        qf[kc] = *(const half8*)(Qbh + (size_t)(q0 + l31) * 64 + kc * 16 + lh * 8);

    floatx16 O[2];
#pragma unroll
    for (int i = 0; i < 2; i++)
#pragma unroll
        for (int r = 0; r < 16; r++) O[i][r] = 0.0f;
    float lsum = 0.0f;

    unsigned int w16[16];   // P of tile t-1, packed fp16 words (reg-resident)
    half8 vf[4][2];         // V^T A-operand frags of tile t-1 (reg)

    // ---- prologue: stage tile 0, prefetch tile 1 ----
    int4 kpre[2], vpre[2];
    kpre[0] = *(const int4*)(Kbh + c0row * 64 + ck8);
    kpre[1] = *(const int4*)(Kbh + c1row * 64 + ck8);
    vpre[0] = *(const int4*)(Vbh + (size_t)c0row * 2048 + ck8);
    vpre[1] = *(const int4*)(Vbh + (size_t)c1row * 2048 + ck8);
    *(int2*)&Kbuf[0][c0row * 68 + ck8]     = make_int2(kpre[0].x, kpre[0].y);
    *(int2*)&Kbuf[0][c0row * 68 + ck8 + 4] = make_int2(kpre[0].z, kpre[0].w);
    *(int2*)&Kbuf[0][c1row * 68 + ck8]     = make_int2(kpre[1].x, kpre[1].y);
    *(int2*)&Kbuf[0][c1row * 68 + ck8 + 4] = make_int2(kpre[1].z, kpre[1].w);
    *(int2*)&Vbuf[0][c0row * 68 + ck8]     = make_int2(vpre[0].x, vpre[0].y);
    *(int2*)&Vbuf[0][c0row * 68 + ck8 + 4] = make_int2(vpre[0].z, vpre[0].w);
    *(int2*)&Vbuf[0][c1row * 68 + ck8]     = make_int2(vpre[1].x, vpre[1].y);
    *(int2*)&Vbuf[0][c1row * 68 + ck8 + 4] = make_int2(vpre[1].z, vpre[1].w);
    kpre[0] = *(const int4*)(Kbh + 4096 + c0row * 64 + ck8);
    kpre[1] = *(const int4*)(Kbh + 4096 + c1row * 64 + ck8);
    vpre[0] = *(const int4*)(Vbh + 64 + (size_t)c0row * 2048 + ck8);
    vpre[1] = *(const int4*)(Vbh + 64 + (size_t)c1row * 2048 + ck8);
    tile_barrier();

    for (int kt = 0; kt < 32; kt++) {
        const int cur = kt & 1;
        const _Float16* Kc = Kbuf[cur];
        const _Float16* Vc = Vbuf[cur];

        if (kt > 0) {
            // D: O += V^T(t-1) * P(t-1); P assembled in-register (permlane)
            __builtin_amdgcn_s_setprio(1);
#pragma unroll
            for (int kc = 0; kc < 4; kc++) {
                int i0 = (kc >> 1) * 4 + (kc & 1) * 2;
                half8 pf = pv_frag(w16, i0);
                O[0] = MFMA_F16(vf[kc][0], pf, O[0], 0, 0, 0);
                O[1] = MFMA_F16(vf[kc][1], pf, O[1], 0, 0, 0);
            }
            __builtin_amdgcn_s_setprio(0);
        }

        // F: stage tile t+1 into the other buffer (regs hold tile t+1)
        if (kt < 31) {
            _Float16* Kd = Kbuf[cur ^ 1];
            _Float16* Vd = Vbuf[cur ^ 1];
            *(int2*)&Kd[c0row * 68 + ck8]     = make_int2(kpre[0].x, kpre[0].y);
            *(int2*)&Kd[c0row * 68 + ck8 + 4] = make_int2(kpre[0].z, kpre[0].w);
            *(int2*)&Kd[c1row * 68 + ck8]     = make_int2(kpre[1].x, kpre[1].y);
            *(int2*)&Kd[c1row * 68 + ck8 + 4] = make_int2(kpre[1].z, kpre[1].w);
            *(int2*)&Vd[c0row * 68 + ck8]     = make_int2(vpre[0].x, vpre[0].y);
            *(int2*)&Vd[c0row * 68 + ck8 + 4] = make_int2(vpre[0].z, vpre[0].w);
            *(int2*)&Vd[c1row * 68 + ck8]     = make_int2(vpre[1].x, vpre[1].y);
            *(int2*)&Vd[c1row * 68 + ck8 + 4] = make_int2(vpre[1].z, vpre[1].w);
        }
        // G: prefetch tile t+2 (rides across tile_barrier — no vmcnt drain)
        if (kt < 30) {
            const _Float16* Ksrc = Kbh + (size_t)(kt + 2) * 4096;
            const _Float16* Vsrc = Vbh + (size_t)(kt + 2) * 64;
            kpre[0] = *(const int4*)(Ksrc + c0row * 64 + ck8);
            kpre[1] = *(const int4*)(Ksrc + c1row * 64 + ck8);
            vpre[0] = *(const int4*)(Vsrc + (size_t)c0row * 2048 + ck8);
            vpre[1] = *(const int4*)(Vsrc + (size_t)c1row * 2048 + ck8);
        }

        // B: V frags(t) -> regs (used for PV at iter t+1; buffer gets
        // overwritten at iter t+1, so read now)
#pragma unroll
        for (int kc = 0; kc < 4; kc++) {
            vf[kc][0] = ld_frag_lds(&Vc[(l31)*68      + kc * 16 + lh * 8]);
            vf[kc][1] = ld_frag_lds(&Vc[(32 + l31)*68 + kc * 16 + lh * 8]);
        }

        // C: S^T(t) = K * Q^T  (kc-outer: the two ms-chains interleave)
        floatx16 Sf[2];
#pragma unroll
        for (int i = 0; i < 2; i++)
#pragma unroll
            for (int r = 0; r < 16; r++) Sf[i][r] = 0.0f;
        __builtin_amdgcn_s_setprio(1);
#pragma unroll
        for (int kc = 0; kc < 4; kc++) {
#pragma unroll
            for (int ms = 0; ms < 2; ms++) {
                half8 kf = ld_frag_lds(&Kc[(ms * 32 + l31) * 68 + kc * 16 + lh * 8]);
                Sf[ms] = MFMA_F16(kf, qf[kc], Sf[ms], 0, 0, 0);
            }
        }
        __builtin_amdgcn_s_setprio(0);

        // E: static softmax — P(t) = exp2(S), pack to regs, accumulate l
        float rsA = 0.0f, rsB = 0.0f;
#pragma unroll
        for (int i = 0; i < 8; i++) {
            int ms = i >> 2, g = i & 3;
            float p0 = fast_exp2(Sf[ms][4 * g + 0]);
            float p1 = fast_exp2(Sf[ms][4 * g + 1]);
            float p2 = fast_exp2(Sf[ms][4 * g + 2]);
            float p3 = fast_exp2(Sf[ms][4 * g + 3]);
            rsA += p0 + p1;
            rsB += p2 + p3;
            w16[2 * i + 0] = pk2(p0, p1);
            w16[2 * i + 1] = pk2(p2, p3);
        }
        lsum += rsA + rsB;

        tile_barrier();
    }

    // ---- epilogue: PV for the last tile (register-only, no barrier) ----
    __builtin_amdgcn_s_setprio(1);
#pragma unroll
    for (int kc = 0; kc < 4; kc++) {
        int i0 = (kc >> 1) * 4 + (kc & 1) * 2;
        half8 pf = pv_frag(w16, i0);
        O[0] = MFMA_F16(vf[kc][0], pf, O[0], 0, 0, 0);
        O[1] = MFMA_F16(vf[kc][1], pf, O[1], 0, 0, 0);
    }
    __builtin_amdgcn_s_setprio(0);

    // combine key-halves' l (lanes l, l+32 share q), normalize, store
    lsum += __shfl_xor(lsum, 32);
    float inv = 1.0f / lsum;
    int q = q0 + l31;
#pragma unroll
    for (int hs = 0; hs < 2; hs++) {
#pragma unroll
        for (int g = 0; g < 4; g++) {
            *(half4*)&AO[(size_t)(b * 2048 + q) * 512 + h * 64 + hs * 32 + g * 8 + lh * 4] =
                pack4(O[hs][4 * g + 0] * inv, O[hs][4 * g + 1] * inv,
                      O[hs][4 * g + 2] * inv, O[hs][4 * g + 3] * inv);
        }
    }
}

// ---------------------------------------------------------------------------
extern "C" void kernel_launch(void* const* d_in, const int* in_sizes, int n_in,
                              void* d_out, int out_size, void* d_ws, size_t ws_size,
                              hipStream_t stream) {
    const float* key   = (const float*)d_in[0];
    const float* query = (const float*)d_in[1];
    const float* value = (const float*)d_in[2];
    const float* Wq    = (const float*)d_in[3];
    const float* Wk    = (const float*)d_in[4];
    const float* Wv    = (const float*)d_in[5];
    const float* Wo    = (const float*)d_in[6];
    const float* bo    = (const float*)d_in[7];

    // Workspace (halfs): Wt[4*512*512] | Qh | Kh | Vt | AO  (69.2 MB)
    _Float16* ws = (_Float16*)d_ws;
    _Float16* Wt = ws;
    _Float16* Qh = ws + 1048576;
    _Float16* Kh = Qh + 8388608;
    _Float16* Vt = Kh + 8388608;
    _Float16* AO = Vt + 8388608;

    const float C1 = 0.18033688011112042f;   // log2(e)/sqrt(64), folded into Q

    wcvt_kernel<<<dim3(256), dim3(256), 0, stream>>>(Wq, Wk, Wv, Wo, Wt);

    qkv_gemm<<<dim3(4, 128, 3), dim3(256), 0, stream>>>(query, key, value, Wt,
                                                        Qh, Kh, Vt, C1);

    attn_kernel<<<dim3(16, 8, 8), dim3(256), 0, stream>>>(Qh, Kh, Vt, AO);

    out_gemm<<<dim3(4, 128), dim3(256), 0, stream>>>(AO, Wt + 3 * 262144, bo,
                                                     (float*)d_out);
}